// Round 1
// 179.831 us; speedup vs baseline: 1.0067x; 1.0067x over previous
//
#include <hip/hip_runtime.h>
#include <stdint.h>

// EMA along contiguous T axis — pipelined persistent-block version.
//
// Previous version (one block per sequence, load->sync->scan->sync->store):
// HBM 30% of peak, VALUBusy 9%, 0 bank conflicts -> phase-serialization /
// latency bound (~9000 cyc/block vs ~1500 cyc of issue work).
//
// This version: grid = 768 blocks (3/CU, LDS-limited), block owns sequences
// seq = bid + s*gridDim. Double-buffered LDS tile, depth-2 prefetch via
// global_load_lds, counted s_waitcnt vmcnt (never 0 in steady state), raw
// s_barrier, all big-tile LDS ops in inline asm (opaque to the waitcnt
// legalizer). Scan math: A-side analytic (A = d^k), so the cross-thread
// scan carries only B, and the second per-thread pass is a dependency-free
// fixup out_j = d^(j+1)*s_in + B_j.

constexpr int T_LEN    = 6000;
constexpr int KPT      = 24;    // elems/thread; 250 threads cover 6000; chunk 96 B (16B-aligned)
constexpr int BLOCK    = 256;   // 4 waves
constexpr int TILE_PAD = 6144;  // padded so unguarded chunks (tid<256) stay in-bounds
constexpr int G4       = T_LEN / 4;  // 1500 float4 granules

typedef float f32x4 __attribute__((ext_vector_type(4)));

__device__ __forceinline__ uint32_t lds_off(const void* p) {
    return (uint32_t)(uintptr_t)(const __attribute__((address_space(3))) void*)p;
}

__global__ __launch_bounds__(BLOCK) void ema_pipe(
    const float* __restrict__ x, const float* __restrict__ init,
    const float* __restrict__ wptr, float* __restrict__ out, int nseq)
{
    __shared__ __align__(16) float tile[2][TILE_PAD];
    __shared__ float waveB[4];

    const int tid  = threadIdx.x;
    const int lane = tid & 63;
    const int wid  = tid >> 6;
    const int bid  = blockIdx.x;
    const int G    = gridDim.x;
    const int ns   = (nseq - bid + G - 1) / G;   // sequences for this block
    if (ns <= 0) return;

    const float w = fminf(fmaxf(wptr[0], 0.0f), 1.0f);
    const float d = 1.0f - w;

    // ---- hoisted data-independent constants ----
    float pw[KPT];                        // pw[j] = d^(j+1)
    { float p = d;
      #pragma unroll
      for (int j = 0; j < KPT; ++j) { pw[j] = p; p *= d; } }
    const float q = pw[KPT-1];            // d^KPT: per-thread A aggregate
    float qp[8];                          // q^(2^k)
    qp[0] = q;
    #pragma unroll
    for (int k = 1; k < 8; ++k) qp[k] = qp[k-1] * qp[k-1];
    const float q64 = qp[6];              // wave A aggregate
    float qlane = 1.0f;                   // q^lane
    #pragma unroll
    for (int k = 0; k < 6; ++k) if ((lane >> k) & 1) qlane *= qp[k];
    float qtid = qlane;                   // q^tid
    if (wid & 1) qtid *= qp[6];
    if (wid & 2) qtid *= qp[7];

    // ---- per-seq initial states preloaded: loop body must contain no
    //      compiler-tracked VMEM loads (keeps the vmcnt ledger exact) ----
    float i0=0,i1=0,i2=0,i3=0,i4=0,i5=0,i6=0,i7=0;
    i0 = init[bid];
    if (ns > 1) i1 = init[bid + G];
    if (ns > 2) i2 = init[bid + 2*G];
    if (ns > 3) i3 = init[bid + 3*G];
    if (ns > 4) i4 = init[bid + 4*G];
    if (ns > 5) i5 = init[bid + 5*G];
    if (ns > 6) i6 = init[bid + 6*G];
    if (ns > 7) i7 = init[bid + 7*G];

    // exactly 6 vmem instructions per wave (round 5 partially masked,
    // every wave keeps >=1 active lane)
    auto prefetch = [&](int buf, int seq) {
        const float* src = x + (size_t)seq * T_LEN;
        #pragma unroll
        for (int i = 0; i < 5; ++i) {
            int idx = tid + i * BLOCK;
            __builtin_amdgcn_global_load_lds(
                (const __attribute__((address_space(1))) void*)(src + idx * 4),
                (__attribute__((address_space(3))) void*)&tile[buf][idx * 4],
                16, 0, 0);
        }
        int idx = tid + 5 * BLOCK;
        if (idx < G4)
            __builtin_amdgcn_global_load_lds(
                (const __attribute__((address_space(1))) void*)(src + idx * 4),
                (__attribute__((address_space(3))) void*)&tile[buf][idx * 4],
                16, 0, 0);
    };

    // ---- prologue: depth-2 prefetch ----
    prefetch(0, bid);
    if (ns > 1) prefetch(1, bid + G);

    for (int s = 0; s < ns; ++s) {
        const int cur = s & 1;
        const int seq = bid + s * G;

        // ledger: after P_s exactly {S_(s-1), P_(s+1)} = 12 vmem ops are
        // issued in steady state; 6 on first/last iteration.
        if (s == 0) {
            if (ns == 1) asm volatile("s_waitcnt vmcnt(0)" ::: "memory");
            else         asm volatile("s_waitcnt vmcnt(6)" ::: "memory");
        } else if (s == ns - 1) {
            asm volatile("s_waitcnt vmcnt(6)" ::: "memory");
        } else {
            asm volatile("s_waitcnt vmcnt(12)" ::: "memory");
        }
        __builtin_amdgcn_s_barrier();        // tile[cur] fully staged

        float s0 = i0;
        if (s == 1) s0 = i1;
        if (s == 2) s0 = i2;
        if (s == 3) s0 = i3;
        if (s == 4) s0 = i4;
        if (s == 5) s0 = i5;
        if (s == 6) s0 = i6;
        if (s == 7) s0 = i7;

        // ---- phase 1: per-thread zero-state chain over 24 elements ----
        f32x4 r0, r1, r2, r3, r4, r5;
        {
            uint32_t a = lds_off(&tile[cur][tid * KPT]);
            asm volatile(
                "ds_read_b128 %0, %6 offset:0\n\t"
                "ds_read_b128 %1, %6 offset:16\n\t"
                "ds_read_b128 %2, %6 offset:32\n\t"
                "ds_read_b128 %3, %6 offset:48\n\t"
                "ds_read_b128 %4, %6 offset:64\n\t"
                "ds_read_b128 %5, %6 offset:80\n\t"
                "s_waitcnt lgkmcnt(0)"
                : "=&v"(r0), "=&v"(r1), "=&v"(r2), "=&v"(r3), "=&v"(r4), "=&v"(r5)
                : "v"(a));
        }
        float xv[KPT];
        xv[0]=r0.x;  xv[1]=r0.y;  xv[2]=r0.z;  xv[3]=r0.w;
        xv[4]=r1.x;  xv[5]=r1.y;  xv[6]=r1.z;  xv[7]=r1.w;
        xv[8]=r2.x;  xv[9]=r2.y;  xv[10]=r2.z; xv[11]=r2.w;
        xv[12]=r3.x; xv[13]=r3.y; xv[14]=r3.z; xv[15]=r3.w;
        xv[16]=r4.x; xv[17]=r4.y; xv[18]=r4.z; xv[19]=r4.w;
        xv[20]=r5.x; xv[21]=r5.y; xv[22]=r5.z; xv[23]=r5.w;
        float Bv[KPT];
        {
            float acc = 0.0f;
            #pragma unroll
            for (int j = 0; j < KPT; ++j) { acc = fmaf(w, xv[j], d * acc); Bv[j] = acc; }
        }

        // ---- phase 2: cross-thread scan of B (A analytic) ----
        float b = Bv[KPT - 1];
        #pragma unroll
        for (int k = 0; k < 6; ++k) {
            float pb = __shfl_up(b, 1u << k, 64);
            if (lane >= (1 << k)) b = fmaf(qp[k], pb, b);
        }
        if (lane == 63) {
            uint32_t aw = lds_off(&waveB[wid]);
            asm volatile("ds_write_b32 %0, %1" :: "v"(aw), "v"(b) : "memory");
        }
        asm volatile("s_waitcnt lgkmcnt(0)" ::: "memory");
        __builtin_amdgcn_s_barrier();
        float wb0, wb1, wb2;
        {
            uint32_t aw = lds_off(&waveB[0]);
            asm volatile(
                "ds_read_b32 %0, %3 offset:0\n\t"
                "ds_read_b32 %1, %3 offset:4\n\t"
                "ds_read_b32 %2, %3 offset:8\n\t"
                "s_waitcnt lgkmcnt(0)"
                : "=&v"(wb0), "=&v"(wb1), "=&v"(wb2)
                : "v"(aw));
        }
        float pB = 0.0f;
        if (wid > 0) pB = wb0;
        if (wid > 1) pB = fmaf(q64, pB, wb1);
        if (wid > 2) pB = fmaf(q64, pB, wb2);

        float eb = __shfl_up(b, 1, 64);
        if (lane == 0) eb = 0.0f;
        const float Bex  = fmaf(qlane, pB, eb);
        const float sin_ = fmaf(qtid, s0, Bex);

        // ---- phase 3: dependency-free fixup + write back ----
        float ov[KPT];
        #pragma unroll
        for (int j = 0; j < KPT; ++j) ov[j] = fmaf(pw[j], sin_, Bv[j]);
        {
            f32x4 o0 = {ov[0],  ov[1],  ov[2],  ov[3]};
            f32x4 o1 = {ov[4],  ov[5],  ov[6],  ov[7]};
            f32x4 o2 = {ov[8],  ov[9],  ov[10], ov[11]};
            f32x4 o3 = {ov[12], ov[13], ov[14], ov[15]};
            f32x4 o4 = {ov[16], ov[17], ov[18], ov[19]};
            f32x4 o5 = {ov[20], ov[21], ov[22], ov[23]};
            uint32_t a = lds_off(&tile[cur][tid * KPT]);
            asm volatile(
                "ds_write_b128 %6, %0 offset:0\n\t"
                "ds_write_b128 %6, %1 offset:16\n\t"
                "ds_write_b128 %6, %2 offset:32\n\t"
                "ds_write_b128 %6, %3 offset:48\n\t"
                "ds_write_b128 %6, %4 offset:64\n\t"
                "ds_write_b128 %6, %5 offset:80\n\t"
                :
                : "v"(o0), "v"(o1), "v"(o2), "v"(o3), "v"(o4), "v"(o5), "v"(a)
                : "memory");
        }
        asm volatile("s_waitcnt lgkmcnt(0)" ::: "memory");
        __builtin_amdgcn_s_barrier();        // results visible block-wide

        // ---- phase 4: coalesced store (exactly 6 vmem ops per wave) ----
        f32x4 v0, v1, v2, v3, v4, v5;
        {
            uint32_t a = lds_off(&tile[cur][0]) + (uint32_t)tid * 16u;
            asm volatile(
                "ds_read_b128 %0, %6 offset:0\n\t"
                "ds_read_b128 %1, %6 offset:4096\n\t"
                "ds_read_b128 %2, %6 offset:8192\n\t"
                "ds_read_b128 %3, %6 offset:12288\n\t"
                "ds_read_b128 %4, %6 offset:16384\n\t"
                "ds_read_b128 %5, %6 offset:20480\n\t"
                "s_waitcnt lgkmcnt(0)"
                : "=&v"(v0), "=&v"(v1), "=&v"(v2), "=&v"(v3), "=&v"(v4), "=&v"(v5)
                : "v"(a));
        }
        {
            f32x4* os4 = (f32x4*)(out + (size_t)seq * T_LEN);
            os4[tid]        = v0;
            os4[tid + 256]  = v1;
            os4[tid + 512]  = v2;
            os4[tid + 768]  = v3;
            os4[tid + 1024] = v4;
            if (tid + 1280 < G4) os4[tid + 1280] = v5;
        }

        // ---- tail: refill freed buffer. Safe without a barrier: prefetch
        // and store-read use the identical tid+i*256 granule mapping, so a
        // wave only overwrites the region it itself just read. ----
        if (s + 2 < ns) prefetch(cur, bid + (s + 2) * G);
    }
}

extern "C" void kernel_launch(void* const* d_in, const int* in_sizes, int n_in,
                              void* d_out, int out_size, void* d_ws, size_t ws_size,
                              hipStream_t stream) {
    const float* mag_spec = (const float*)d_in[0];
    const float* initial_state = (const float*)d_in[1];
    const float* weights = (const float*)d_in[2];
    float* out = (float*)d_out;

    const int nseq = in_sizes[1];  // 8*2*257 = 4112

    int G = 768;                                   // 3 blocks/CU (LDS-limited)
    if ((nseq + 7) / 8 > G) G = (nseq + 7) / 8;    // keep ns <= 8 (i0..i7)
    if (G > nseq) G = nseq;

    ema_pipe<<<G, BLOCK, 0, stream>>>(mag_spec, initial_state, weights, out, nseq);
}